// Round 7
// baseline (373.244 us; speedup 1.0000x reference)
//
#include <hip/hip_runtime.h>
#include <hip/hip_bf16.h>

#define NEG_SLOPE 0.2f
#define BN_RS 0.9999950000374997f   // 1/sqrt(1 + 1e-5)

typedef __attribute__((ext_vector_type(8))) _Float16 f16x8;  // MFMA A/B frag (4 VGPR)
typedef __attribute__((ext_vector_type(2))) _Float16 f16x2;
typedef __attribute__((ext_vector_type(4))) float f32x4;     // MFMA acc

// split fp32 -> fp16 hi (RNE) + fp16 lo (RNE of residual); hi+lo carries ~22 bits
__device__ __forceinline__ void store_split(float w, _Float16* H, _Float16* L, size_t off) {
  _Float16 h = (_Float16)w;
  H[off] = h;
  L[off] = (_Float16)(w - (float)h);
}

// ---------------- CSR build: two-level bucket radix (bucket = dst>>8) ----------------
// Requires N <= 65536 (src packed into 16 bits). N = 50000 here.

__global__ void zero256(int* p) { p[threadIdx.x] = 0; }

__global__ void eb_hist(const int* __restrict__ ei, int* __restrict__ bucketSize, int E) {
  __shared__ int h[256];
  int tid = threadIdx.x;
  h[tid] = 0;
  __syncthreads();
  for (int i = blockIdx.x * 256 + tid; i < E; i += gridDim.x * 256)
    atomicAdd(&h[ei[E + i] >> 8], 1);
  __syncthreads();
  if (h[tid]) atomicAdd(&bucketSize[tid], h[tid]);
}

__global__ void eb_scan(const int* __restrict__ bucketSize, int* __restrict__ edgeStart,
                        int* __restrict__ cursor, int* __restrict__ csrStart, int N) {
  __shared__ int sd[256];
  int tid = threadIdx.x;
  int v = bucketSize[tid];
  sd[tid] = v;
  __syncthreads();
  for (int off = 1; off < 256; off <<= 1) {
    int t = (tid >= off) ? sd[tid - off] : 0;
    __syncthreads();
    sd[tid] += t;
    __syncthreads();
  }
  int excl = sd[tid] - v;
  edgeStart[tid] = excl;
  cursor[tid] = excl;
  csrStart[tid] = excl + min(tid << 8, N);
  if (tid == 255) edgeStart[256] = sd[255];
}

#define PCH 4096
__global__ __launch_bounds__(256) void eb_part(const int* __restrict__ ei,
                                               int* __restrict__ cursor,
                                               unsigned* __restrict__ staging, int E) {
  __shared__ unsigned val[PCH];
  __shared__ unsigned char bk[PCH];
  __shared__ int cnt[256];
  __shared__ int base[256];
  int tid = threadIdx.x;
  cnt[tid] = 0;
  __syncthreads();
  int e0 = blockIdx.x * PCH;
  int n = min(PCH, E - e0);
  for (int j = tid; j < n; j += 256) {
    int s = ei[e0 + j], d = ei[E + e0 + j];
    val[j] = ((unsigned)(d & 255) << 16) | (unsigned)s;
    int b = d >> 8;
    bk[j] = (unsigned char)b;
    atomicAdd(&cnt[b], 1);
  }
  __syncthreads();
  if (cnt[tid]) base[tid] = atomicAdd(&cursor[tid], cnt[tid]);
  __syncthreads();
  for (int j = tid; j < n; j += 256) {
    int b = bk[j];
    int off = atomicSub(&cnt[b], 1) - 1;
    staging[base[b] + off] = val[j];
  }
}

__global__ __launch_bounds__(256) void eb_csr(
    const unsigned* __restrict__ staging, const int* __restrict__ edgeStart,
    const int* __restrict__ csrStart, int* __restrict__ rowptr,
    int* __restrict__ csr, int N) {
  __shared__ int deg[256];
  __shared__ int sc[256];
  __shared__ int ex[256];
  int b = blockIdx.x, tid = threadIdx.x;
  int n0 = b << 8;
  int nn = min(256, N - n0);
  deg[tid] = (tid < nn) ? 1 : 0;   // self-loop
  __syncthreads();
  int s0 = edgeStart[b], s1 = edgeStart[b + 1];
  for (int j = s0 + tid; j < s1; j += 256)
    atomicAdd(&deg[staging[j] >> 16], 1);
  __syncthreads();
  int dv = deg[tid];
  sc[tid] = dv;
  __syncthreads();
  for (int off = 1; off < 256; off <<= 1) {
    int t = (tid >= off) ? sc[tid - off] : 0;
    __syncthreads();
    sc[tid] += t;
    __syncthreads();
  }
  int incl = sc[tid];
  int cbase = csrStart[b];
  ex[tid] = incl - dv;
  if (tid < nn) {
    rowptr[n0 + tid + 1] = cbase + incl;
    csr[cbase + incl - 1] = n0 + tid;   // self-loop at end of row
  }
  if (b == 0 && tid == 0) rowptr[0] = 0;
  deg[tid] = 0;                          // reuse as per-node cursor
  __syncthreads();
  for (int j = s0 + tid; j < s1; j += 256) {
    unsigned v = staging[j];
    int dl = v >> 16;
    int src = v & 0xFFFF;
    int off = atomicAdd(&deg[dl], 1);
    csr[cbase + ex[dl] + off] = src;
  }
}

// ---------------- weight prep ----------------
// conv W[128][128] -> Wt hi/lo fp16 [144][128]: rows 0..127 = W^T split,
// rows 128..131 = combined attn-src cols (es = A @ ws), 132..135 attn-dst, 136..143 zero.
// M1 [128][64] -> [64][128]; M2 [64][128] -> [128][64].
__device__ __forceinline__ void wprep_conv(const float* __restrict__ W,
                                           const float* __restrict__ as_,
                                           const float* __restrict__ ad_,
                                           _Float16* __restrict__ H, _Float16* __restrict__ L,
                                           int lb, int tid) {
  if (lb < 64) {                       // transpose region
    int idx = lb * 256 + tid;
    int k = idx >> 7, p = idx & 127;
    store_split(W[k * 128 + p], H, L, (size_t)p * 128 + k);
  } else if (lb < 68) {                // attn-combined rows
    int idx = (lb - 64) * 256 + tid;   // 1024 entries: 8 rows x 128 k
    int rl = idx >> 7, k = idx & 127;
    const float* a = (rl < 4) ? as_ : ad_;
    int h = rl & 3;
    float s = 0.f;
#pragma unroll
    for (int f = 0; f < 32; f++) s += W[k * 128 + h * 32 + f] * a[h * 32 + f];
    store_split(s, H, L, (size_t)(128 + rl) * 128 + k);
  } else {                             // zero pad rows 136..143
    int idx = (lb - 68) * 256 + tid;
    int rl = idx >> 7, k = idx & 127;
    H[(size_t)(136 + rl) * 128 + k] = (_Float16)0.f;
    L[(size_t)(136 + rl) * 128 + k] = (_Float16)0.f;
  }
}

__global__ void wprep_all(
    const float* __restrict__ W1, const float* __restrict__ a1s, const float* __restrict__ a1d,
    _Float16* __restrict__ W1H, _Float16* __restrict__ W1L,
    const float* __restrict__ W2, const float* __restrict__ a2s, const float* __restrict__ a2d,
    _Float16* __restrict__ W2H, _Float16* __restrict__ W2L,
    const float* __restrict__ W3, const float* __restrict__ a3s, const float* __restrict__ a3d,
    _Float16* __restrict__ W3H, _Float16* __restrict__ W3L,
    const float* __restrict__ M1, _Float16* __restrict__ M1H, _Float16* __restrict__ M1L,
    const float* __restrict__ M2, _Float16* __restrict__ M2H, _Float16* __restrict__ M2L) {
  int b = blockIdx.x, tid = threadIdx.x;
  if (b < 72)       wprep_conv(W1, a1s, a1d, W1H, W1L, b, tid);
  else if (b < 144) wprep_conv(W2, a2s, a2d, W2H, W2L, b - 72, tid);
  else if (b < 216) wprep_conv(W3, a3s, a3d, W3H, W3L, b - 144, tid);
  else if (b < 248) {                  // M1: [128][64] -> [64][128]
    int idx = (b - 216) * 256 + tid;
    int k = idx >> 6, p = idx & 63;
    store_split(M1[k * 64 + p], M1H, M1L, (size_t)p * 128 + k);
  } else {                             // M2: [64][128] -> [128][64]
    int idx = (b - 248) * 256 + tid;
    int k = idx >> 7, p = idx & 127;
    store_split(M2[k * 128 + p], M2H, M2L, (size_t)p * 64 + k);
  }
}

// ---------------- GEMM via fp16 MFMA, W split hi/lo ----------------
// C[N x PST](fp16) = A[N x K] @ W; A fp16 (or fp32 for layer 0, cvt in staging).
// D = A@Wh + A@Wl. AUG=1: PT=PST+16, extra tile -> es/ed fp32 (attn scores fused).
// EPI 0: raw store. EPI 1: bn(relu(acc + bias)).
template <int PT, int PST, int K, int EPI, int AUG, typename TA>
__global__ __launch_bounds__(256) void gemm_f16(
    const TA* __restrict__ A, const _Float16* __restrict__ WtH,
    const _Float16* __restrict__ WtL, _Float16* __restrict__ C, int N,
    const float* __restrict__ bias, const float* __restrict__ gamma,
    const float* __restrict__ beta, float* __restrict__ esb,
    float* __restrict__ edb) {
  constexpr int NTILE = PT / 16;
  constexpr int CTB = NTILE / 4;      // base col-tiles per wave
  constexpr int REM = NTILE % 4;      // 0 or 1 (extra tile on wave 0)
  constexpr int KT = K / 32;
  __shared__ _Float16 As[128 * 32];
  __shared__ _Float16 WsH[PT * 32];
  __shared__ _Float16 WsL[PT * 32];
  const int tid = threadIdx.x;
  const int wave = tid >> 6, lane = tid & 63;
  const int quad = lane >> 4, l16 = lane & 15;
  const int row0 = blockIdx.x * 128;
  const bool xw = (REM != 0) && (wave == 0);

  f32x4 acc[8][CTB + (REM ? 1 : 0)];
#pragma unroll
  for (int rt = 0; rt < 8; rt++)
#pragma unroll
    for (int nt = 0; nt < CTB + (REM ? 1 : 0); nt++) acc[rt][nt] = (f32x4){0.f, 0.f, 0.f, 0.f};

  for (int kc = 0; kc < KT; ++kc) {
    // ---- stage A: 128 rows x 32 halves ----
    {
      int r = tid >> 1, part = tid & 1;
      int gr = row0 + r;
      _Float16* dst = &As[r * 32 + part * 16];
      if (gr < N) {
        const TA* src = A + (size_t)gr * K + kc * 32 + part * 16;
        if constexpr (sizeof(TA) == 4) {     // fp32 input (layer 0): cvt
          f16x8 h0, h1;
#pragma unroll
          for (int j = 0; j < 8; j++) { h0[j] = (_Float16)src[j]; h1[j] = (_Float16)src[8 + j]; }
          *(f16x8*)dst = h0; *(f16x8*)(dst + 8) = h1;
        } else {                              // fp16: raw copy
          uint4 v0 = *(const uint4*)src;
          uint4 v1 = *(const uint4*)(src + 8);
          *(uint4*)dst = v0; *(uint4*)(dst + 8) = v1;
        }
      } else {
        *(uint4*)dst = make_uint4(0, 0, 0, 0);
        *(uint4*)(dst + 8) = make_uint4(0, 0, 0, 0);
      }
    }
    // ---- stage W hi/lo: PT rows x 32 halves each ----
    for (int idx = tid; idx < PT * 2; idx += 256) {
      int isL = idx >= PT;
      int p = isL ? idx - PT : idx;
      const _Float16* src = (isL ? WtL : WtH) + (size_t)p * K + kc * 32;
      _Float16* dst = (isL ? WsL : WsH) + p * 32;
      uint4 a0 = *(const uint4*)src;       uint4 a1 = *(const uint4*)(src + 8);
      uint4 a2 = *(const uint4*)(src + 16); uint4 a3 = *(const uint4*)(src + 24);
      *(uint4*)dst = a0; *(uint4*)(dst + 8) = a1;
      *(uint4*)(dst + 16) = a2; *(uint4*)(dst + 24) = a3;
    }
    __syncthreads();

    f16x8 bh[CTB], bl[CTB], bhE, blE;
#pragma unroll
    for (int nt = 0; nt < CTB; nt++) {
      int p = (wave * CTB + nt) * 16 + l16;
      bh[nt] = *(f16x8*)&WsH[p * 32 + quad * 8];
      bl[nt] = *(f16x8*)&WsL[p * 32 + quad * 8];
    }
    if constexpr (REM) {
      if (xw) {
        int p = 4 * CTB * 16 + l16;
        bhE = *(f16x8*)&WsH[p * 32 + quad * 8];
        blE = *(f16x8*)&WsL[p * 32 + quad * 8];
      }
    }
#pragma unroll
    for (int rt = 0; rt < 8; rt++) {
      f16x8 a = *(f16x8*)&As[(rt * 16 + l16) * 32 + quad * 8];
#pragma unroll
      for (int nt = 0; nt < CTB; nt++) {
        acc[rt][nt] = __builtin_amdgcn_mfma_f32_16x16x32_f16(a, bh[nt], acc[rt][nt], 0, 0, 0);
        acc[rt][nt] = __builtin_amdgcn_mfma_f32_16x16x32_f16(a, bl[nt], acc[rt][nt], 0, 0, 0);
      }
      if constexpr (REM) {
        if (xw) {
          acc[rt][CTB] = __builtin_amdgcn_mfma_f32_16x16x32_f16(a, bhE, acc[rt][CTB], 0, 0, 0);
          acc[rt][CTB] = __builtin_amdgcn_mfma_f32_16x16x32_f16(a, blE, acc[rt][CTB], 0, 0, 0);
        }
      }
    }
    __syncthreads();
  }

  // ---- epilogue (C/D layout: col=lane&15, row=quad*4+reg) ----
#pragma unroll
  for (int nt = 0; nt < CTB; nt++) {
    int c = (wave * CTB + nt) * 16 + l16;
    float bi = 0.f, ga = 0.f, be = 0.f;
    if constexpr (EPI == 1) { bi = bias[c]; ga = gamma[c] * BN_RS; be = beta[c]; }
#pragma unroll
    for (int rt = 0; rt < 8; rt++)
#pragma unroll
      for (int g = 0; g < 4; g++) {
        int r = row0 + rt * 16 + quad * 4 + g;
        if (r < N) {
          float v = acc[rt][nt][g];
          if constexpr (EPI == 1) { v += bi; v = v > 0.f ? v : 0.f; v = v * ga + be; }
          C[(size_t)r * PST + c] = (_Float16)v;
        }
      }
  }
  if constexpr (REM) {
    if (wave == 0 && l16 < 8) {
      float* dstb = (l16 < 4) ? esb : edb;
      int h = l16 & 3;
#pragma unroll
      for (int rt = 0; rt < 8; rt++)
#pragma unroll
        for (int g = 0; g < 4; g++) {
          int r = row0 + rt * 16 + quad * 4 + g;
          if (r < N) dstb[(size_t)r * 4 + h] = acc[rt][CTB][g];
        }
    }
  }
}

// ---------------- GAT aggregation: one wave per dst node, two-phase ----------------
// Phase 1 (per 16-edge chunk): lane l handles combo (edge l>>2, head l&3):
//   computes leaky+exp ONCE per combo (was 16x redundant), stores w to LDS.
// Phase 2: per edge, w from LDS (broadcast), csr wave-uniform (scalar pipe),
//   hx base uniform (SGPR) + lane offset. Intra-wave LDS ordering -> no barrier.
// MODE 0: out fp16 [N,128] = relu(S/z + bias). MODE 1: out fp32 [N,32] = mean_heads + bias.
template <int MODE>
__global__ __launch_bounds__(256) void gat_agg(
    const _Float16* __restrict__ hx, const int* __restrict__ rowptr,
    const int* __restrict__ csr, const float* __restrict__ es,
    const float* __restrict__ ed, const float* __restrict__ bias,
    void* __restrict__ outp, int N) {
  __shared__ float wbuf[4][16][4];   // [wave][edge-slot][head]
  int wid = (blockIdx.x * 256 + threadIdx.x) >> 6;
  if (wid >= N) return;
  int wave = threadIdx.x >> 6;
  int lane = threadIdx.x & 63;
  int head = lane >> 4;
  int j4 = lane >> 2;                // phase-1 edge slot 0..15
  int h4 = lane & 3;                 // phase-1 head
  int beg = rowptr[wid], end = rowptr[wid + 1];
  float edv4 = ed[wid * 4 + h4];
  float ax = 0.f, ay = 0.f, z = 0.f;
  const _Float16* hb = hx + 2 * lane;

  for (int c = beg; c < end; c += 16) {
    int m = end - c; if (m > 16) m = 16;
    // ---- phase 1: batch-compute softmax weights for this chunk ----
    if (j4 < m) {
      int s = csr[c + j4];
      float t = es[s * 4 + h4] + edv4;
      t = t > 0.f ? t : NEG_SLOPE * t;
      wbuf[wave][j4][h4] = __expf(t);
    }
    // ---- phase 2: weighted accumulation ----
    int j = 0;
    for (; j + 4 <= m; j += 4) {
      int e = c + j;
      int s0 = csr[e], s1 = csr[e + 1], s2 = csr[e + 2], s3 = csr[e + 3];
      float w0 = wbuf[wave][j + 0][head];
      float w1 = wbuf[wave][j + 1][head];
      float w2 = wbuf[wave][j + 2][head];
      float w3 = wbuf[wave][j + 3][head];
      f16x2 h0 = *(const f16x2*)(hb + (size_t)s0 * 128);
      f16x2 h1 = *(const f16x2*)(hb + (size_t)s1 * 128);
      f16x2 h2 = *(const f16x2*)(hb + (size_t)s2 * 128);
      f16x2 h3 = *(const f16x2*)(hb + (size_t)s3 * 128);
      z += (w0 + w1) + (w2 + w3);
      ax = fmaf(w0, (float)h0[0], ax); ay = fmaf(w0, (float)h0[1], ay);
      ax = fmaf(w1, (float)h1[0], ax); ay = fmaf(w1, (float)h1[1], ay);
      ax = fmaf(w2, (float)h2[0], ax); ay = fmaf(w2, (float)h2[1], ay);
      ax = fmaf(w3, (float)h3[0], ax); ay = fmaf(w3, (float)h3[1], ay);
    }
    for (; j < m; ++j) {
      int s = csr[c + j];
      float w = wbuf[wave][j][head];
      f16x2 hv = *(const f16x2*)(hb + (size_t)s * 128);
      z += w;
      ax = fmaf(w, (float)hv[0], ax);
      ay = fmaf(w, (float)hv[1], ay);
    }
  }
  float inv = 1.f / (z + 1e-16f);
  float vx = ax * inv, vy = ay * inv;
  if (MODE == 0) {
    vx += bias[2 * lane]; vy += bias[2 * lane + 1];
    vx = vx > 0.f ? vx : 0.f;  vy = vy > 0.f ? vy : 0.f;
    f16x2 o; o[0] = (_Float16)vx; o[1] = (_Float16)vy;
    *(f16x2*)((_Float16*)outp + (size_t)wid * 128 + 2 * lane) = o;
  } else {
    vx += __shfl_xor(vx, 16); vx += __shfl_xor(vx, 32);
    vy += __shfl_xor(vy, 16); vy += __shfl_xor(vy, 32);
    if (lane < 16) {
      float ox = vx * 0.25f + bias[2 * lane];
      float oy = vy * 0.25f + bias[2 * lane + 1];
      *(float2*)((float*)outp + (size_t)wid * 32 + 2 * lane) = make_float2(ox, oy);
    }
  }
}

extern "C" void kernel_launch(void* const* d_in, const int* in_sizes, int n_in,
                              void* d_out, int out_size, void* d_ws, size_t ws_size,
                              hipStream_t stream) {
  const float* x   = (const float*)d_in[0];
  const int*   ei  = (const int*)d_in[1];
  const float* W1  = (const float*)d_in[2];
  const float* a1s = (const float*)d_in[3];
  const float* a1d = (const float*)d_in[4];
  const float* b1  = (const float*)d_in[5];
  const float* W2  = (const float*)d_in[6];
  const float* a2s = (const float*)d_in[7];
  const float* a2d = (const float*)d_in[8];
  const float* b2  = (const float*)d_in[9];
  const float* M1w = (const float*)d_in[10];
  const float* M1b = (const float*)d_in[11];
  const float* g1  = (const float*)d_in[12];
  const float* be1 = (const float*)d_in[13];
  const float* M2w = (const float*)d_in[14];
  const float* M2b = (const float*)d_in[15];
  const float* g2  = (const float*)d_in[16];
  const float* be2 = (const float*)d_in[17];
  const float* W3  = (const float*)d_in[18];
  const float* a3s = (const float*)d_in[19];
  const float* a3d = (const float*)d_in[20];
  const float* b3  = (const float*)d_in[21];

  const int N = in_sizes[0] / 128;
  const int E = in_sizes[1] / 2;

  char* w = (char*)d_ws;
  _Float16* bufA = (_Float16*)w; w += (size_t)N * 128 * 2;
  _Float16* bufB = (_Float16*)w; w += (size_t)N * 128 * 2;
  _Float16* bufM = (_Float16*)w; w += (size_t)N * 64 * 2;
  float* esb  = (float*)w; w += (size_t)N * 4 * 4;
  float* edb  = (float*)w; w += (size_t)N * 4 * 4;
  int* rowptr = (int*)w;   w += (size_t)(N + 1) * 4;
  int* csr    = (int*)w;   w += (size_t)(E + N) * 4;
  unsigned* staging = (unsigned*)w; w += (size_t)E * 4;
  int* bucketSize = (int*)w; w += 256 * 4;
  int* edgeStart  = (int*)w; w += 257 * 4;
  int* cursor     = (int*)w; w += 256 * 4;
  int* csrStart   = (int*)w; w += 256 * 4;
  // split-fp16 transposed weights (hi/lo)
  _Float16* W1H = (_Float16*)w; w += 144 * 128 * 2;
  _Float16* W1L = (_Float16*)w; w += 144 * 128 * 2;
  _Float16* W2H = (_Float16*)w; w += 144 * 128 * 2;
  _Float16* W2L = (_Float16*)w; w += 144 * 128 * 2;
  _Float16* W3H = (_Float16*)w; w += 144 * 128 * 2;
  _Float16* W3L = (_Float16*)w; w += 144 * 128 * 2;
  _Float16* M1H = (_Float16*)w; w += 64 * 128 * 2;
  _Float16* M1L = (_Float16*)w; w += 64 * 128 * 2;
  _Float16* M2H = (_Float16*)w; w += 128 * 64 * 2;
  _Float16* M2L = (_Float16*)w; w += 128 * 64 * 2;

  const int gb = (N + 127) / 128;
  const int aggb = (N + 3) / 4;        // 4 waves per block
  const int nbk = (N + 255) / 256;     // buckets
  const int pbk = (E + PCH - 1) / PCH;

  // ---- weight prep (single dispatch) ----
  wprep_all<<<280, 256, 0, stream>>>(W1, a1s, a1d, W1H, W1L,
                                     W2, a2s, a2d, W2H, W2L,
                                     W3, a3s, a3d, W3H, W3L,
                                     M1w, M1H, M1L, M2w, M2H, M2L);

  // ---- CSR build: bucket radix partition ----
  zero256<<<1, 256, 0, stream>>>(bucketSize);
  eb_hist<<<256, 256, 0, stream>>>(ei, bucketSize, E);
  eb_scan<<<1, 256, 0, stream>>>(bucketSize, edgeStart, cursor, csrStart, N);
  eb_part<<<pbk, 256, 0, stream>>>(ei, cursor, staging, E);
  eb_csr<<<nbk, 256, 0, stream>>>(staging, edgeStart, csrStart, rowptr, csr, N);

  // ---- layer 0: conv0(+attn) -> agg(relu+bias) -> MLP x2 ----
  gemm_f16<144, 128, 128, 0, 1, float><<<gb, 256, 0, stream>>>(
      x, W1H, W1L, bufA, N, nullptr, nullptr, nullptr, esb, edb);
  gat_agg<0><<<aggb, 256, 0, stream>>>(bufA, rowptr, csr, esb, edb, b1, bufB, N);
  gemm_f16<64, 64, 128, 1, 0, _Float16><<<gb, 256, 0, stream>>>(
      bufB, M1H, M1L, bufM, N, M1b, g1, be1, nullptr, nullptr);
  gemm_f16<128, 128, 64, 1, 0, _Float16><<<gb, 256, 0, stream>>>(
      bufM, M2H, M2L, bufA, N, M2b, g2, be2, nullptr, nullptr);

  // ---- layer 1: conv1(+attn) -> agg(relu+bias) ----
  gemm_f16<144, 128, 128, 0, 1, _Float16><<<gb, 256, 0, stream>>>(
      bufA, W2H, W2L, bufB, N, nullptr, nullptr, nullptr, esb, edb);
  gat_agg<0><<<aggb, 256, 0, stream>>>(bufB, rowptr, csr, esb, edb, b2, bufA, N);

  // ---- layer 2: conv2(+attn) -> agg (mean heads, +b3) ----
  gemm_f16<144, 128, 128, 0, 1, _Float16><<<gb, 256, 0, stream>>>(
      bufA, W3H, W3L, bufB, N, nullptr, nullptr, nullptr, esb, edb);
  gat_agg<1><<<aggb, 256, 0, stream>>>(bufB, rowptr, csr, esb, edb, b3, d_out, N);
}